// Round 7
// baseline (3309.108 us; speedup 1.0000x reference)
//
#include <hip/hip_runtime.h>
#include <hip/hip_bf16.h>
#include <math.h>

// ---------------------------------------------------------------------------
// Weight pre-transposes into lane-coalesced float4 layouts (R5 lesson: the
// lane-major dim must be LAST; 16B granules per lane):
//   Wx (3,3,Cin,Cout) -> wxT[((tap*(CINP/4)+c4c)*Cout + co)*4 + j]  (c pad 0)
//   Wh (3,3,F,4F)     -> whT[(((tap*4+g)*(F/4)+c4c)*F + f)*4 + j]
// All six tensors transposed in ONE kernel (launch-overhead matters: ~60
// graph nodes cost ~10-15us each -> R6 collapses node count 60 -> 18).
// ---------------------------------------------------------------------------
__device__ __forceinline__ void wx_elem(const float* __restrict__ src,
                                        float* __restrict__ dst, int i,
                                        int Cin, int CinP, int Cout)
{
  int j = i & 3; int rem = i >> 2;
  int co = rem % Cout; rem /= Cout;
  int c4c = rem % (CinP / 4); int tap = rem / (CinP / 4);
  int c = c4c * 4 + j;
  dst[i] = (c < Cin) ? src[((size_t)tap * Cin + c) * Cout + co] : 0.f;
}

__device__ __forceinline__ void wh_elem(const float* __restrict__ src,
                                        float* __restrict__ dst, int i, int F)
{
  int j = i & 3; int rem = i >> 2;
  int f = rem % F; rem /= F;
  int c4c = rem % (F / 4); rem /= (F / 4);
  int g = rem & 3; int tap = rem >> 2;
  int c = c4c * 4 + j;
  dst[i] = src[((size_t)tap * F + c) * 4 * F + g * F + f];
}

__global__ void transpose_all(
    const float* __restrict__ W1x, const float* __restrict__ W2x,
    const float* __restrict__ W3x, const float* __restrict__ W1h,
    const float* __restrict__ W2h, const float* __restrict__ W3h,
    float* __restrict__ Wx1T, float* __restrict__ Wx2T, float* __restrict__ Wx3T,
    float* __restrict__ Wh1T, float* __restrict__ Wh2T, float* __restrict__ Wh3T)
{
  int i = blockIdx.x * 256 + threadIdx.x;
  if (i < 2304)        wx_elem(W1x, Wx1T, i,          3,  4,  64);
  else if (i < 20736)  wx_elem(W2x, Wx2T, i - 2304,   16, 16, 128);
  else if (i < 94464)  wx_elem(W3x, Wx3T, i - 20736,  32, 32, 256);
  else if (i < 103680) wh_elem(W1h, Wh1T, i - 94464,  16);
  else if (i < 140544) wh_elem(W2h, Wh2T, i - 103680, 32);
  else if (i < 288000) wh_elem(W3h, Wh3T, i - 140544, 64);
}

// ---------------------------------------------------------------------------
// Direct 3x3 'SAME' conv, NHWC, fp32, with bias. Register blocking: thread
// computes NG output channels (co = tid%COL + g*COL) for PPT positions.
// Weight fetch: NG coalesced float4 loads per c4-iter.
// NOTE: `#pragma unroll 1` on the channel loop is load-bearing (R0 spill).
// ---------------------------------------------------------------------------
template<int H, int W, int Cin, int Cout, int TH, int TW, int COL, int NG>
__global__ __launch_bounds__(256) void conv3x3_bias(
    const float* __restrict__ in, const float* __restrict__ wtT,
    const float* __restrict__ bias, float* __restrict__ out)
{
  static_assert(COL * NG == Cout, "cout coverage");
  constexpr int CIN_P = (Cin % 4 == 0) ? Cin : ((Cin + 3) / 4) * 4;
  constexpr int TILES_X = W / TW, TILES_Y = H / TH;
  constexpr int PAD_W = TW + 2, PAD_H = TH + 2;
  constexpr int LDS_N = PAD_H * PAD_W * CIN_P;
  constexpr int NPG = 256 / COL;
  constexpr int PPT = TH * TW / NPG;
  __shared__ __align__(16) float tile[LDS_N];

  int blk = blockIdx.x;
  int n = blk / (TILES_X * TILES_Y);
  int trem = blk % (TILES_X * TILES_Y);
  int ty = trem / TILES_X, tx = trem % TILES_X;
  int y0 = ty * TH, x0 = tx * TW;
  const float* inN = in + (size_t)n * H * W * Cin;

  for (int i = threadIdx.x; i < LDS_N; i += 256) {
    int ci = i % CIN_P; int rem = i / CIN_P;
    int xx = rem % PAD_W; int yy = rem / PAD_W;
    int gy = y0 + yy - 1, gx = x0 + xx - 1;
    float v = 0.f;
    if (ci < Cin && gy >= 0 && gy < H && gx >= 0 && gx < W)
      v = inN[((size_t)gy * W + gx) * Cin + ci];
    tile[i] = v;
  }
  __syncthreads();

  int cobase = threadIdx.x % COL;
  int pg = threadIdx.x / COL;
  float* outN = out + (size_t)n * H * W * Cout;

  float acc[NG][PPT];
#pragma unroll
  for (int g = 0; g < NG; ++g) {
    float bco = bias[g * COL + cobase];
#pragma unroll
    for (int j = 0; j < PPT; ++j) acc[g][j] = bco;
  }

  const float4* wt4 = (const float4*)wtT;
#pragma unroll
  for (int kh = 0; kh < 3; ++kh)
#pragma unroll
  for (int kw = 0; kw < 3; ++kw) {
    const float4* wtap = wt4 + (size_t)(kh * 3 + kw) * (CIN_P / 4) * Cout;
#pragma unroll 1
    for (int c4 = 0; c4 < CIN_P; c4 += 4) {
      const float4* wrow = wtap + (size_t)(c4 / 4) * Cout + cobase;
      float4 w[NG];
#pragma unroll
      for (int g = 0; g < NG; ++g) w[g] = wrow[g * COL];
#pragma unroll
      for (int j = 0; j < PPT; ++j) {
        int p = pg * PPT + j;
        int ly = p / TW, lx = p % TW;
        const float4 h4 = *(const float4*)&tile[((ly + kh) * PAD_W + (lx + kw)) * CIN_P + c4];
#pragma unroll
        for (int g = 0; g < NG; ++g)
          acc[g][j] += h4.x * w[g].x + h4.y * w[g].y + h4.z * w[g].z + h4.w * w[g].w;
      }
    }
  }

#pragma unroll
  for (int j = 0; j < PPT; ++j) {
    int p = pg * PPT + j;
    int ly = p / TW, lx = p % TW;
    float* op = &outN[((size_t)(y0 + ly) * W + (x0 + lx)) * Cout + cobase];
#pragma unroll
    for (int g = 0; g < NG; ++g) op[g * COL] = acc[g][j];
  }
}

// ---------------------------------------------------------------------------
// Persistent ConvLSTM LAYER: all TSEQ timesteps in one kernel, separated by a
// device-scope soft grid barrier (per-step arrival counters; all blocks are
// co-resident: grid <= 2 blocks/CU enforced via __launch_bounds__(256,2) and
// resource use ~80 VGPR / <8KB LDS gives >=4 blocks/CU capacity).
// Correctness notes (G16): __threadfence() on the release side writes back
// the XCD-local L2 (buffer_wbl2 sc1) so h stores are visible cross-XCD; the
// acquire side invalidates stale L1/L2. h is stored time-sequenced (unique
// addresses per step) so no stale-L1 address reuse; c is same-thread only.
// ---------------------------------------------------------------------------
__device__ __forceinline__ float hsig(float x) {
  return fminf(fmaxf(0.2f * x + 0.5f, 0.f), 1.f);
}

template<int H, int W, int F, int TH, int TW, int TSEQ>
__global__ __launch_bounds__(256, 2) void lstm_layer(
    const float* __restrict__ gx, long gx_bstride,   // (B,[T],H,W,4F), t inner
    const float* __restrict__ whT,                   // packed, see wh_elem
    float* __restrict__ c,                           // (B,H,W,F)
    float* __restrict__ hseq, long h_bstride,        // (B,[T],H,W,F), t inner
    unsigned int* __restrict__ bar)                  // [TSEQ] counters, zeroed
{
  constexpr int TILES_X = W / TW, TILES_Y = H / TH;
  constexpr int PAD_W = TW + 2, PAD_H = TH + 2;
  constexpr int LDS_N = PAD_H * PAD_W * F;
  __shared__ __align__(16) float tile[LDS_N];

  int blk = blockIdx.x;
  int b = blk / (TILES_X * TILES_Y);
  int trem = blk % (TILES_X * TILES_Y);
  int ty = trem / TILES_X, tx = trem % TILES_X;
  int y0 = ty * TH, x0 = tx * TW;

  constexpr int G = 256 / F;     // position-groups
  constexpr int P = TH * TW;
  constexpr int NP = P / G;      // positions per thread
  int f = threadIdx.x % F;
  int pg = threadIdx.x / F;

  const float4* wh4 = (const float4*)whT;
  float* cb = c + (size_t)b * H * W * F;

#pragma unroll 1
  for (int t = 0; t < TSEQ; ++t) {
    // ---- stage h_{t-1} tile (with halo) into LDS ----
    if (t == 0) {
      for (int i = threadIdx.x; i < LDS_N; i += 256) tile[i] = 0.f;
    } else {
      const float* hb = hseq + (size_t)b * h_bstride + (size_t)(t - 1) * H * W * F;
      for (int i = threadIdx.x; i < LDS_N; i += 256) {
        int ci = i % F; int rem = i / F;
        int xx = rem % PAD_W, yy = rem / PAD_W;
        int gy = y0 + yy - 1, gxp = x0 + xx - 1;
        float v = 0.f;
        if (gy >= 0 && gy < H && gxp >= 0 && gxp < W)
          v = hb[((size_t)gy * W + gxp) * F + ci];
        tile[i] = v;
      }
    }
    __syncthreads();

    // ---- z = gx[t] + conv(h_{t-1}, Wh) ----
    float acc[4][NP];
    const float* gxb = gx + (size_t)b * gx_bstride + (size_t)t * H * W * 4 * F;
#pragma unroll
    for (int j = 0; j < NP; ++j) {
      int p = pg * NP + j;
      int gy = y0 + p / TW, gxp = x0 + p % TW;
      size_t base = ((size_t)gy * W + gxp) * 4 * F;
#pragma unroll
      for (int g = 0; g < 4; ++g) acc[g][j] = gxb[base + g * F + f];
    }

#pragma unroll
    for (int kh = 0; kh < 3; ++kh)
#pragma unroll
    for (int kw = 0; kw < 3; ++kw) {
      int tap = kh * 3 + kw;
#pragma unroll 1
      for (int c4 = 0; c4 < F; c4 += 4) {
        float4 h4[NP];
#pragma unroll
        for (int j = 0; j < NP; ++j) {
          int p = pg * NP + j;
          int ly = p / TW, lx = p % TW;
          h4[j] = *(const float4*)&tile[((ly + kh) * PAD_W + (lx + kw)) * F + c4];
        }
        // coalesced: consecutive f lanes -> consecutive float4
        float4 w0 = wh4[((size_t)(tap * 4 + 0) * (F / 4) + c4 / 4) * F + f];
        float4 w1 = wh4[((size_t)(tap * 4 + 1) * (F / 4) + c4 / 4) * F + f];
        float4 w2 = wh4[((size_t)(tap * 4 + 2) * (F / 4) + c4 / 4) * F + f];
        float4 w3 = wh4[((size_t)(tap * 4 + 3) * (F / 4) + c4 / 4) * F + f];
#pragma unroll
        for (int j = 0; j < NP; ++j) {
          acc[0][j] += h4[j].x * w0.x + h4[j].y * w0.y + h4[j].z * w0.z + h4[j].w * w0.w;
          acc[1][j] += h4[j].x * w1.x + h4[j].y * w1.y + h4[j].z * w1.z + h4[j].w * w1.w;
          acc[2][j] += h4[j].x * w2.x + h4[j].y * w2.y + h4[j].z * w2.z + h4[j].w * w2.w;
          acc[3][j] += h4[j].x * w3.x + h4[j].y * w3.y + h4[j].z * w3.z + h4[j].w * w3.w;
        }
      }
    }

    // ---- gate math, c/h update ----
    float* hb2 = hseq + (size_t)b * h_bstride + (size_t)t * H * W * F;
#pragma unroll
    for (int j = 0; j < NP; ++j) {
      int p = pg * NP + j;
      int gy = y0 + p / TW, gxp = x0 + p % TW;
      size_t idx = ((size_t)gy * W + gxp) * F + f;
      float zi = acc[0][j], zf = acc[1][j], zc = acc[2][j], zo = acc[3][j];
      float cold = (t == 0) ? 0.f : cb[idx];
      float cn = hsig(zf) * cold + hsig(zi) * tanhf(zc);
      cb[idx] = cn;
      hb2[idx] = hsig(zo) * tanhf(cn);
    }

    // ---- device-scope grid barrier (skip after last step) ----
    if (t < TSEQ - 1) {
      __syncthreads();
      if (threadIdx.x == 0) {
        __threadfence();   // release: wb local L2 so h is visible cross-XCD
        __hip_atomic_fetch_add(&bar[t], 1u, __ATOMIC_RELEASE, __HIP_MEMORY_SCOPE_AGENT);
        while (__hip_atomic_load(&bar[t], __ATOMIC_ACQUIRE, __HIP_MEMORY_SCOPE_AGENT)
               < (unsigned)gridDim.x)
          __builtin_amdgcn_s_sleep(8);
        __threadfence();   // acquire: invalidate stale L1/L2 lines
      }
      __syncthreads();
    }
  }
}

// ---------------------------------------------------------------------------
// BatchNorm (affine, eps=1e-3) + 2x2 spatial max.
// ---------------------------------------------------------------------------
__global__ void bnpool_kernel(const float* __restrict__ in,
                              const float* __restrict__ g, const float* __restrict__ be,
                              const float* __restrict__ m, const float* __restrict__ v,
                              float* __restrict__ out, int total, int H, int W, int F)
{
  int i = blockIdx.x * 256 + threadIdx.x;
  if (i >= total) return;
  int f = i % F; int rem = i / F;
  int x = rem % (W / 2); rem /= (W / 2);
  int y = rem % (H / 2); int nt = rem / (H / 2);
  float scale = g[f] * rsqrtf(v[f] + 1e-3f);
  float shift = be[f] - m[f] * scale;
  const float* base = in + (((size_t)nt * H + 2 * y) * W + 2 * x) * F + f;
  float a0 = base[0] * scale + shift;
  float a1 = base[F] * scale + shift;
  float a2 = base[(size_t)W * F] * scale + shift;
  float a3 = base[(size_t)W * F + F] * scale + shift;
  out[i] = fmaxf(fmaxf(a0, a1), fmaxf(a2, a3));
}

// (8,16,16,64) slot -> (8,8,8,64) flattened to (8,4096); bstride = batch stride
__global__ void poolhw_kernel(const float* __restrict__ in, float* __restrict__ out,
                              int total, long bstride)
{
  int i = blockIdx.x * 256 + threadIdx.x;
  if (i >= total) return;
  int f = i % 64; int rem = i / 64;
  int x = rem % 8; rem /= 8;
  int y = rem % 8; int b = rem / 8;
  const float* base = in + (size_t)b * bstride + (((size_t)2 * y) * 16 + 2 * x) * 64 + f;
  float a0 = base[0], a1 = base[64], a2 = base[16 * 64], a3 = base[16 * 64 + 64];
  out[i] = fmaxf(fmaxf(a0, a1), fmaxf(a2, a3));
}

// ---------------------------------------------------------------------------
// Dense (8,K)@(K,N): k-split partials + reduce (no atomics).
// ---------------------------------------------------------------------------
__global__ __launch_bounds__(256) void dense_partial(
    const float* __restrict__ x, const float* __restrict__ w,
    float* __restrict__ part, int K, int N, int kchunk)
{
  extern __shared__ __align__(16) float xs[];  // kchunk*8, layout [kk][b]
  int kb = blockIdx.y;
  int k0 = kb * kchunk;
  int klen = min(kchunk, K - k0);
  for (int i = threadIdx.x; i < klen * 8; i += 256) {
    int kk = i >> 3, b = i & 7;
    xs[i] = x[(size_t)b * K + k0 + kk];
  }
  __syncthreads();
  int co = blockIdx.x * 256 + threadIdx.x;
  if (co >= N) return;
  float acc[8];
#pragma unroll
  for (int b = 0; b < 8; ++b) acc[b] = 0.f;
  const float4* xs4 = (const float4*)xs;
  const float* wp = w + (size_t)k0 * N + co;
#pragma unroll 4
  for (int kk = 0; kk < klen; ++kk) {
    float wv = wp[(size_t)kk * N];
    float4 lo = xs4[kk * 2], hi = xs4[kk * 2 + 1];
    acc[0] += lo.x * wv; acc[1] += lo.y * wv;
    acc[2] += lo.z * wv; acc[3] += lo.w * wv;
    acc[4] += hi.x * wv; acc[5] += hi.y * wv;
    acc[6] += hi.z * wv; acc[7] += hi.w * wv;
  }
#pragma unroll
  for (int b = 0; b < 8; ++b)
    part[((size_t)kb * 8 + b) * N + co] = acc[b];
}

__global__ __launch_bounds__(256) void dense_reduce(
    const float* __restrict__ part, const float* __restrict__ bias,
    float* __restrict__ out, int N, int S)
{
  int co = blockIdx.x * 256 + threadIdx.x;
  int b = blockIdx.y;
  if (co >= N) return;
  float acc = bias[co];
#pragma unroll 4
  for (int kb = 0; kb < S; ++kb)
    acc += part[((size_t)kb * 8 + b) * N + co];
  out[(size_t)b * N + co] = acc;
}

// Final (8,100)@(100,10)+b4 then @(10,1)+bc -> (8,1). LDS-staged (latency).
__global__ void dense_tail(const float* __restrict__ d3,
                           const float* __restrict__ w4, const float* __restrict__ b4,
                           const float* __restrict__ wc, const float* __restrict__ bc,
                           float* __restrict__ out)
{
  __shared__ float sd3[800];
  __shared__ float sw4[1000];
  __shared__ float swc[10];
  __shared__ float d4[8][10];
  int t = threadIdx.x;
  for (int i = t; i < 800; i += 256) sd3[i] = d3[i];
  for (int i = t; i < 1000; i += 256) sw4[i] = w4[i];
  if (t < 10) swc[t] = wc[t];
  __syncthreads();
  if (t < 80) {
    int b = t / 10, co = t % 10;
    float acc = b4[co];
#pragma unroll 4
    for (int k = 0; k < 100; ++k) acc += sd3[b * 100 + k] * sw4[k * 10 + co];
    d4[b][co] = acc;
  }
  __syncthreads();
  if (t < 8) {
    float acc = bc[0];
#pragma unroll
    for (int j = 0; j < 10; ++j) acc += d4[t][j] * swc[j];
    out[t] = acc;
  }
}

// ---------------------------------------------------------------------------
extern "C" void kernel_launch(void* const* d_in, const int* in_sizes, int n_in,
                              void* d_out, int out_size, void* d_ws, size_t ws_size,
                              hipStream_t stream)
{
  const float* x   = (const float*)d_in[0];
  const float* W1x = (const float*)d_in[1];
  const float* W1h = (const float*)d_in[2];
  const float* b1  = (const float*)d_in[3];
  const float* g1  = (const float*)d_in[4];
  const float* be1 = (const float*)d_in[5];
  const float* m1  = (const float*)d_in[6];
  const float* v1  = (const float*)d_in[7];
  const float* W2x = (const float*)d_in[8];
  const float* W2h = (const float*)d_in[9];
  const float* b2  = (const float*)d_in[10];
  const float* g2  = (const float*)d_in[11];
  const float* be2 = (const float*)d_in[12];
  const float* m2  = (const float*)d_in[13];
  const float* v2  = (const float*)d_in[14];
  const float* W3x = (const float*)d_in[15];
  const float* W3h = (const float*)d_in[16];
  const float* b3  = (const float*)d_in[17];
  const float* Wd1 = (const float*)d_in[18];
  const float* bd1 = (const float*)d_in[19];
  const float* Wd2 = (const float*)d_in[20];
  const float* bd2 = (const float*)d_in[21];
  const float* Wd3 = (const float*)d_in[22];
  const float* bd3 = (const float*)d_in[23];
  const float* Wd4 = (const float*)d_in[24];
  const float* bd4 = (const float*)d_in[25];
  const float* Wc  = (const float*)d_in[26];
  const float* bc  = (const float*)d_in[27];

  // workspace layout (bytes, 256-aligned), lifetime-based reuse
  char* ws = (char*)d_ws;
  size_t off = 0;
  auto alloc = [&](size_t bytes) { size_t r = off; off = (off + bytes + 255) & ~(size_t)255; return r; };
  size_t oR0    = alloc(100663296);  // gx1 -> gx2 -> gx3; then part1/part2
  size_t oR1    = alloc(25165824);   // hseq1 -> hseq2 -> hseq3(12-slot)
  size_t oR2    = alloc(6291456);    // pool1 -> pool2
  size_t oR3    = alloc(2097152);    // c buffer
  size_t oflat  = alloc(131072);
  size_t od1    = alloc(320000);
  size_t od2    = alloc(32000);
  size_t od3    = alloc(3200);
  size_t opart3 = alloc(64000);     // 20*8*100*4
  size_t oWx1T  = alloc(9216);
  size_t oWx2T  = alloc(73728);
  size_t oWx3T  = alloc(294912);
  size_t oWh1T  = alloc(36864);
  size_t oWh2T  = alloc(147456);
  size_t oWh3T  = alloc(589824);
  size_t ocnt   = alloc(144);       // 36 barrier counters
  (void)ws_size; (void)in_sizes; (void)n_in; (void)out_size;

  float* gx1   = (float*)(ws + oR0);
  float* gx2   = (float*)(ws + oR0);
  float* gx3   = (float*)(ws + oR0);
  float* part1 = (float*)(ws + oR0);             // 20.5 MB (gx dead)
  float* part2 = (float*)(ws + oR0 + 33554432);  // 4 MB
  float* hseq1 = (float*)(ws + oR1);
  float* hseq2 = (float*)(ws + oR1);
  float* hseq3 = (float*)(ws + oR1);             // (B,12,16,16,64) = 6.3 MB
  float* pool1 = (float*)(ws + oR2);
  float* pool2 = (float*)(ws + oR2);
  float* cbuf  = (float*)(ws + oR3);
  float* flat  = (float*)(ws + oflat);
  float* d1    = (float*)(ws + od1);
  float* d2    = (float*)(ws + od2);
  float* d3b   = (float*)(ws + od3);
  float* part3 = (float*)(ws + opart3);
  float* Wx1T  = (float*)(ws + oWx1T);
  float* Wx2T  = (float*)(ws + oWx2T);
  float* Wx3T  = (float*)(ws + oWx3T);
  float* Wh1T  = (float*)(ws + oWh1T);
  float* Wh2T  = (float*)(ws + oWh2T);
  float* Wh3T  = (float*)(ws + oWh3T);
  unsigned int* cnt = (unsigned int*)(ws + ocnt);

  const int B = 8, T = 12;

  // ---- barrier counters zero + all weight transposes (1 node each) ----
  hipMemsetAsync(cnt, 0, 144, stream);
  transpose_all<<<1125, 256, 0, stream>>>(W1x, W2x, W3x, W1h, W2h, W3h,
                                          Wx1T, Wx2T, Wx3T, Wh1T, Wh2T, Wh3T);

  // ---- Layer 1: 64x64, Cin=3(pad 4), F=16 ----
  conv3x3_bias<64, 64, 3, 64, 4, 8, 32, 2><<<96 * 128, 256, 0, stream>>>(x, Wx1T, b1, gx1);
  lstm_layer<64, 64, 16, 8, 8, 12><<<B * 64, 256, 0, stream>>>(
      gx1, (long)T * 64 * 64 * 64, Wh1T, cbuf, hseq1, (long)T * 64 * 64 * 16, cnt + 0);
  {
    int total = B * T * 32 * 32 * 16;
    bnpool_kernel<<<(total + 255) / 256, 256, 0, stream>>>(hseq1, g1, be1, m1, v1, pool1, total, 64, 64, 16);
  }

  // ---- Layer 2: 32x32, Cin=16, F=32 ----
  conv3x3_bias<32, 32, 16, 128, 4, 8, 32, 4><<<96 * 32, 256, 0, stream>>>(pool1, Wx2T, b2, gx2);
  lstm_layer<32, 32, 32, 4, 4, 12><<<B * 64, 256, 0, stream>>>(
      gx2, (long)T * 32 * 32 * 128, Wh2T, cbuf, hseq2, (long)T * 32 * 32 * 32, cnt + 12);
  {
    int total = B * T * 16 * 16 * 32;
    bnpool_kernel<<<(total + 255) / 256, 256, 0, stream>>>(hseq2, g2, be2, m2, v2, pool2, total, 32, 32, 32);
  }

  // ---- Layer 3: 16x16, Cin=32, F=64 (12-slot h sequence; take slot 11) ----
  conv3x3_bias<16, 16, 32, 256, 4, 8, 64, 4><<<96 * 8, 256, 0, stream>>>(pool2, Wx3T, b3, gx3);
  lstm_layer<16, 16, 64, 2, 4, 12><<<B * 32, 256, 0, stream>>>(
      gx3, (long)T * 16 * 16 * 256, Wh3T, cbuf, hseq3, (long)T * 16 * 16 * 64, cnt + 24);
  poolhw_kernel<<<(32768 + 255) / 256, 256, 0, stream>>>(
      hseq3 + (size_t)11 * 16 * 16 * 64, flat, 32768, (long)T * 16 * 16 * 64);

  // ---- Dense chain ----
  dense_partial<<<dim3(40, 64), 256, 64 * 8 * 4, stream>>>(flat, Wd1, part1, 4096, 10000, 64);
  dense_reduce<<<dim3(40, 8), 256, 0, stream>>>(part1, bd1, d1, 10000, 64);
  dense_partial<<<dim3(4, 125), 256, 80 * 8 * 4, stream>>>(d1, Wd2, part2, 10000, 1000, 80);
  dense_reduce<<<dim3(4, 8), 256, 0, stream>>>(part2, bd2, d2, 1000, 125);
  dense_partial<<<dim3(1, 20), 256, 50 * 8 * 4, stream>>>(d2, Wd3, part3, 1000, 100, 50);
  dense_reduce<<<dim3(1, 8), 256, 0, stream>>>(part3, bd3, d3b, 100, 20);
  dense_tail<<<1, 256, 0, stream>>>(d3b, Wd4, bd4, Wc, bc, (float*)d_out);
}